// Round 1
// baseline (141.082 us; speedup 1.0000x reference)
//
#include <hip/hip_runtime.h>
#include <stdint.h>

#define IN_DIM 2048
#define OUT_DIM 2048
#define BATCH 4096
#define KDIM (2 * IN_DIM)  // 4096
#define BN_EPS 1e-5f

typedef __attribute__((ext_vector_type(8))) short bf16x8;
typedef __attribute__((ext_vector_type(4))) float f32x4;

__device__ __forceinline__ unsigned short f2bf(float f) {
  union { float f; unsigned u; } v; v.f = f;
  unsigned r = v.u + 0x7FFFu + ((v.u >> 16) & 1u);  // RNE
  return (unsigned short)(r >> 16);
}

// K1a: A = [wavelet(x) | x] bf16, row-major (BATCH x KDIM)
__global__ void prep_act(const float* __restrict__ x,
                         const float* __restrict__ scale,
                         const float* __restrict__ translate,
                         unsigned short* __restrict__ A) {
  int e = (blockIdx.x * 256 + threadIdx.x) * 4;  // element idx in (BATCH*IN_DIM)
  int b = e / IN_DIM;
  int i = e % IN_DIM;
  float4 xv = *(const float4*)(x + e);
  float4 sv = *(const float4*)(scale + i);
  float4 tv = *(const float4*)(translate + i);
  const float c = 0.7511255444649425f;  // pi^-0.25
  float u0 = (xv.x - tv.x) / fmaxf(sv.x, 1e-3f);
  float u1 = (xv.y - tv.y) / fmaxf(sv.y, 1e-3f);
  float u2 = (xv.z - tv.z) / fmaxf(sv.z, 1e-3f);
  float u3 = (xv.w - tv.w) / fmaxf(sv.w, 1e-3f);
  ushort4 wv, xb;
  wv.x = f2bf(c * __cosf(3.0f * u0) * __expf(-0.5f * u0 * u0));
  wv.y = f2bf(c * __cosf(3.0f * u1) * __expf(-0.5f * u1 * u1));
  wv.z = f2bf(c * __cosf(3.0f * u2) * __expf(-0.5f * u2 * u2));
  wv.w = f2bf(c * __cosf(3.0f * u3) * __expf(-0.5f * u3 * u3));
  xb.x = f2bf(xv.x); xb.y = f2bf(xv.y); xb.z = f2bf(xv.z); xb.w = f2bf(xv.w);
  *(ushort4*)(A + (size_t)b * KDIM + i) = wv;
  *(ushort4*)(A + (size_t)b * KDIM + IN_DIM + i) = xb;
}

// K1b: W = [wave_weight | 0.3*base_weight] bf16, row-major (OUT_DIM x KDIM)
__global__ void prep_w(const float* __restrict__ ww,
                       const float* __restrict__ bw,
                       unsigned short* __restrict__ W) {
  int e = (blockIdx.x * 256 + threadIdx.x) * 4;  // element idx in (OUT_DIM*IN_DIM)
  int o = e / IN_DIM;
  int k = e % IN_DIM;
  float4 a = *(const float4*)(ww + e);
  float4 b = *(const float4*)(bw + e);
  ushort4 wa, wb;
  wa.x = f2bf(a.x); wa.y = f2bf(a.y); wa.z = f2bf(a.z); wa.w = f2bf(a.w);
  wb.x = f2bf(0.3f * b.x); wb.y = f2bf(0.3f * b.y);
  wb.z = f2bf(0.3f * b.z); wb.w = f2bf(0.3f * b.w);
  *(ushort4*)(W + (size_t)o * KDIM + k) = wa;
  *(ushort4*)(W + (size_t)o * KDIM + IN_DIM + k) = wb;
}

// K2: Y[b][o] = sum_k A[b][k]*W[o][k], 128x128 tile, BK=64, 4 waves (2x2)
__global__ __launch_bounds__(256) void gemm_bf16(
    const unsigned short* __restrict__ A,
    const unsigned short* __restrict__ W,
    float* __restrict__ Y) {
  __shared__ unsigned short As[128 * 64];
  __shared__ unsigned short Ws[128 * 64];
  const int tid = threadIdx.x;
  const int lane = tid & 63;
  const int wave = tid >> 6;
  const int wr = wave >> 1;   // wave row (0..1), 64 output rows each
  const int wc = wave & 1;    // wave col (0..1), 64 output cols each
  const int brow = blockIdx.y * 128;
  const int bcol = blockIdx.x * 128;

  f32x4 acc[4][4];
#pragma unroll
  for (int m = 0; m < 4; ++m)
#pragma unroll
    for (int n = 0; n < 4; ++n)
      acc[m][n] = (f32x4){0.f, 0.f, 0.f, 0.f};

  // staging: issue i stages 32 rows x 128B; this thread covers
  // row = i*32 + wave*8 + lane/8, byte col = (lane%8)*16
  const int srow = wave * 8 + (lane >> 3);
  const int scolb = (lane & 7) * 16;

  for (int k0 = 0; k0 < KDIM; k0 += 64) {
#pragma unroll
    for (int i = 0; i < 4; ++i) {
      int row = i * 32 + srow;
      const char* ga = (const char*)A + (size_t)(brow + row) * (KDIM * 2) + k0 * 2 + scolb;
      __builtin_amdgcn_global_load_lds(
          (const __attribute__((address_space(1))) void*)ga,
          (__attribute__((address_space(3))) void*)((char*)As + i * 4096 + wave * 1024),
          16, 0, 0);
    }
#pragma unroll
    for (int i = 0; i < 4; ++i) {
      int row = i * 32 + srow;
      const char* gb = (const char*)W + (size_t)(bcol + row) * (KDIM * 2) + k0 * 2 + scolb;
      __builtin_amdgcn_global_load_lds(
          (const __attribute__((address_space(1))) void*)gb,
          (__attribute__((address_space(3))) void*)((char*)Ws + i * 4096 + wave * 1024),
          16, 0, 0);
    }
    __syncthreads();  // drains vmcnt (global_load_lds) per __syncthreads semantics
#pragma unroll
    for (int kk = 0; kk < 64; kk += 32) {
      bf16x8 af[4], bfr[4];
#pragma unroll
      for (int m = 0; m < 4; ++m)
        af[m] = *(const bf16x8*)&As[(wr * 64 + m * 16 + (lane & 15)) * 64 + kk + ((lane >> 4) * 8)];
#pragma unroll
      for (int n = 0; n < 4; ++n)
        bfr[n] = *(const bf16x8*)&Ws[(wc * 64 + n * 16 + (lane & 15)) * 64 + kk + ((lane >> 4) * 8)];
#pragma unroll
      for (int m = 0; m < 4; ++m)
#pragma unroll
        for (int n = 0; n < 4; ++n)
          acc[m][n] = __builtin_amdgcn_mfma_f32_16x16x32_bf16(af[m], bfr[n], acc[m][n], 0, 0, 0);
    }
    __syncthreads();
  }

  // epilogue: C/D layout col = lane&15, row = (lane>>4)*4 + j  [m89-verified]
  const int r0 = brow + wr * 64 + (lane >> 4) * 4;
  const int c0 = bcol + wc * 64 + (lane & 15);
#pragma unroll
  for (int m = 0; m < 4; ++m)
#pragma unroll
    for (int n = 0; n < 4; ++n)
#pragma unroll
      for (int j = 0; j < 4; ++j)
        Y[(size_t)(r0 + m * 16 + j) * OUT_DIM + (c0 + n * 16)] = acc[m][n][j];
}

// K3a: per-column sums / sums-of-squares over batch (atomics into ws)
__global__ void colstats(const float* __restrict__ Y,
                         float* __restrict__ sums, float* __restrict__ sqs) {
  int col = (blockIdx.x & 7) * 256 + threadIdx.x;
  int r0 = (blockIdx.x >> 3) * 128;
  float s = 0.f, q = 0.f;
  for (int r = 0; r < 128; ++r) {
    float v = Y[(size_t)(r0 + r) * OUT_DIM + col];
    s += v;
    q += v * v;
  }
  atomicAdd(&sums[col], s);
  atomicAdd(&sqs[col], q);
}

// K3b: in-place batchnorm on Y
__global__ void bnorm(float* __restrict__ Y,
                      const float* __restrict__ sums, const float* __restrict__ sqs,
                      const float* __restrict__ gamma, const float* __restrict__ beta) {
  int e = (blockIdx.x * 256 + threadIdx.x) * 4;
  int c = e % OUT_DIM;
  float4 y = *(float4*)(Y + e);
  float4 s = *(const float4*)(sums + c);
  float4 q = *(const float4*)(sqs + c);
  float4 g = *(const float4*)(gamma + c);
  float4 bb = *(const float4*)(beta + c);
  const float invB = 1.0f / (float)BATCH;
  float m0 = s.x * invB, m1 = s.y * invB, m2 = s.z * invB, m3 = s.w * invB;
  float i0 = rsqrtf(q.x * invB - m0 * m0 + BN_EPS);
  float i1 = rsqrtf(q.y * invB - m1 * m1 + BN_EPS);
  float i2 = rsqrtf(q.z * invB - m2 * m2 + BN_EPS);
  float i3 = rsqrtf(q.w * invB - m3 * m3 + BN_EPS);
  y.x = g.x * (y.x - m0) * i0 + bb.x;
  y.y = g.y * (y.y - m1) * i1 + bb.y;
  y.z = g.z * (y.z - m2) * i2 + bb.z;
  y.w = g.w * (y.w - m3) * i3 + bb.w;
  *(float4*)(Y + e) = y;
}

extern "C" void kernel_launch(void* const* d_in, const int* in_sizes, int n_in,
                              void* d_out, int out_size, void* d_ws, size_t ws_size,
                              hipStream_t stream) {
  const float* x         = (const float*)d_in[0];
  const float* scale     = (const float*)d_in[1];
  const float* translate = (const float*)d_in[2];
  const float* ww        = (const float*)d_in[3];
  const float* bw        = (const float*)d_in[4];
  const float* gamma     = (const float*)d_in[5];
  const float* beta      = (const float*)d_in[6];
  float* out = (float*)d_out;

  char* ws = (char*)d_ws;
  unsigned short* A = (unsigned short*)ws;                          // 33,554,432 B
  unsigned short* W = (unsigned short*)(ws + 33554432);             // 16,777,216 B
  float* sums = (float*)(ws + 33554432 + 16777216);                 // 8 KB
  float* sqs = sums + OUT_DIM;                                      // 8 KB

  hipMemsetAsync(sums, 0, 2 * OUT_DIM * sizeof(float), stream);
  prep_act<<<(BATCH * IN_DIM) / 1024, 256, 0, stream>>>(x, scale, translate, A);
  prep_w<<<(OUT_DIM * IN_DIM) / 1024, 256, 0, stream>>>(ww, bw, W);
  dim3 g(OUT_DIM / 128, BATCH / 128);
  gemm_bf16<<<g, 256, 0, stream>>>(A, W, out);
  colstats<<<256, 256, 0, stream>>>(out, sums, sqs);
  bnorm<<<(BATCH * OUT_DIM) / 1024, 256, 0, stream>>>(out, sums, sqs, gamma, beta);
}

// Round 2
// 117.269 us; speedup vs baseline: 1.2031x; 1.2031x over previous
//
#include <hip/hip_runtime.h>
#include <stdint.h>

#define IN_DIM 2048
#define OUT_DIM 2048
#define BATCH 4096
#define KDIM (2 * IN_DIM)   // 4096
#define KROWB (KDIM * 2)    // 8192 bytes per bf16 row
#define NT 64               // K-tiles of 64
#define BN_EPS 1e-5f

typedef __attribute__((ext_vector_type(8))) short bf16x8;
typedef __attribute__((ext_vector_type(4))) float f32x4;

__device__ __forceinline__ unsigned short f2bf(float f) {
  union { float f; unsigned u; } v; v.f = f;
  unsigned r = v.u + 0x7FFFu + ((v.u >> 16) & 1u);  // RNE
  return (unsigned short)(r >> 16);
}

// K1a: A = [wavelet(x) | x] bf16, row-major (BATCH x KDIM)
__global__ void prep_act(const float* __restrict__ x,
                         const float* __restrict__ scale,
                         const float* __restrict__ translate,
                         unsigned short* __restrict__ A) {
  int e = (blockIdx.x * 256 + threadIdx.x) * 4;
  int b = e / IN_DIM;
  int i = e % IN_DIM;
  float4 xv = *(const float4*)(x + e);
  float4 sv = *(const float4*)(scale + i);
  float4 tv = *(const float4*)(translate + i);
  const float c = 0.7511255444649425f;  // pi^-0.25
  float u0 = (xv.x - tv.x) / fmaxf(sv.x, 1e-3f);
  float u1 = (xv.y - tv.y) / fmaxf(sv.y, 1e-3f);
  float u2 = (xv.z - tv.z) / fmaxf(sv.z, 1e-3f);
  float u3 = (xv.w - tv.w) / fmaxf(sv.w, 1e-3f);
  ushort4 wv, xb;
  wv.x = f2bf(c * __cosf(3.0f * u0) * __expf(-0.5f * u0 * u0));
  wv.y = f2bf(c * __cosf(3.0f * u1) * __expf(-0.5f * u1 * u1));
  wv.z = f2bf(c * __cosf(3.0f * u2) * __expf(-0.5f * u2 * u2));
  wv.w = f2bf(c * __cosf(3.0f * u3) * __expf(-0.5f * u3 * u3));
  xb.x = f2bf(xv.x); xb.y = f2bf(xv.y); xb.z = f2bf(xv.z); xb.w = f2bf(xv.w);
  *(ushort4*)(A + (size_t)b * KDIM + i) = wv;
  *(ushort4*)(A + (size_t)b * KDIM + IN_DIM + i) = xb;
}

// K1b: W = [wave_weight | 0.3*base_weight] bf16, row-major (OUT_DIM x KDIM)
__global__ void prep_w(const float* __restrict__ ww,
                       const float* __restrict__ bw,
                       unsigned short* __restrict__ W) {
  int e = (blockIdx.x * 256 + threadIdx.x) * 4;
  int o = e / IN_DIM;
  int k = e % IN_DIM;
  float4 a = *(const float4*)(ww + e);
  float4 b = *(const float4*)(bw + e);
  ushort4 wa, wb;
  wa.x = f2bf(a.x); wa.y = f2bf(a.y); wa.z = f2bf(a.z); wa.w = f2bf(a.w);
  wb.x = f2bf(0.3f * b.x); wb.y = f2bf(0.3f * b.y);
  wb.z = f2bf(0.3f * b.z); wb.w = f2bf(0.3f * b.w);
  *(ushort4*)(W + (size_t)o * KDIM + k) = wa;
  *(ushort4*)(W + (size_t)o * KDIM + IN_DIM + k) = wb;
}

// ---------------- 8-phase GEMM: Y[b][o] = sum_k A[b][k]*W[o][k] ----------------
// BM=128 (batch rows), BN=256 (out cols), BK=64. 8 waves = 2M x 4N, per-wave 64x64.
// LDS ring: 2 parities x {A unit 16K, B0 unit 16K, B1 unit 16K} = 96 KB.
// Units for K-tile t+2 staged at ph3/ph4 of tile t; one vmcnt(6) per K-tile.

#define GLDS(gp, lo) __builtin_amdgcn_global_load_lds( \
    (const __attribute__((address_space(1))) void*)(gp), \
    (__attribute__((address_space(3))) void*)(lds + (lo) + ldsl), 16, 0, 0)

#define STAGE(base_, gptr_, t_) do { \
  GLDS((gptr_) + (size_t)(t_) * 128, (base_)); \
  GLDS((gptr_) + (size_t)(t_) * 128 + (size_t)64 * KROWB, (base_) + 8192); \
} while (0)

#define LDA(dst, P, mh) do { \
  dst[0][0] = *(const bf16x8*)(lds + (P) + rA + (mh) * 4096 +    0 + s0); \
  dst[0][1] = *(const bf16x8*)(lds + (P) + rA + (mh) * 4096 +    0 + s1); \
  dst[1][0] = *(const bf16x8*)(lds + (P) + rA + (mh) * 4096 + 2048 + s0); \
  dst[1][1] = *(const bf16x8*)(lds + (P) + rA + (mh) * 4096 + 2048 + s1); \
} while (0)

#define LDB(dst, P, nh) do { \
  dst[0][0] = *(const bf16x8*)(lds + (P) + bu + rB + (nh) * 4096 +    0 + s0); \
  dst[0][1] = *(const bf16x8*)(lds + (P) + bu + rB + (nh) * 4096 +    0 + s1); \
  dst[1][0] = *(const bf16x8*)(lds + (P) + bu + rB + (nh) * 4096 + 2048 + s0); \
  dst[1][1] = *(const bf16x8*)(lds + (P) + bu + rB + (nh) * 4096 + 2048 + s1); \
} while (0)

#define MMQ(iof, jof, af, bf_) do { \
  __builtin_amdgcn_s_setprio(1); \
  _Pragma("unroll") for (int i2 = 0; i2 < 2; ++i2) \
  _Pragma("unroll") for (int j2 = 0; j2 < 2; ++j2) \
  _Pragma("unroll") for (int k2 = 0; k2 < 2; ++k2) \
    acc[(iof) + i2][(jof) + j2] = __builtin_amdgcn_mfma_f32_16x16x32_bf16( \
        af[i2][k2], bf_[j2][k2], acc[(iof) + i2][(jof) + j2], 0, 0, 0); \
  __builtin_amdgcn_s_setprio(0); \
} while (0)

#define LGKM0() asm volatile("s_waitcnt lgkmcnt(0)" ::: "memory")
#define VMW6()  asm volatile("s_waitcnt vmcnt(6)" ::: "memory")
#define VMW0()  asm volatile("s_waitcnt vmcnt(0)" ::: "memory")
#define BAR()   do { asm volatile("" ::: "memory"); __builtin_amdgcn_s_barrier(); \
                     asm volatile("" ::: "memory"); } while (0)

// KTILE: 4 phases. Reads: ph1 A(mh0)+Bown(nh0)=8, ph2 Bown(nh1)=4, ph3 A(mh1)=4.
// Stages (for t+2): ph3 B0 (freed by ph2), ph4 B1 + A (freed by ph2/ph3).
#define KTILE(p, t, DOSTAGE, VMTAIL) do { \
  const int P = (p) * 49152; \
  LDA(a0, P, 0); LDB(b0f, P, 0); \
  BAR(); MMQ(0, 0, a0, b0f); LGKM0(); BAR(); \
  LDB(b1f, P, 1); \
  BAR(); MMQ(0, 2, a0, b1f); LGKM0(); BAR(); \
  LDA(a1, P, 1); \
  if (DOSTAGE) STAGE(P + 16384, bS0, (t) + 2); \
  BAR(); MMQ(2, 2, a1, b1f); LGKM0(); BAR(); \
  if (DOSTAGE) { STAGE(P + 32768, bS1, (t) + 2); STAGE(P, aS, (t) + 2); } \
  BAR(); MMQ(2, 0, a1, b0f); VMTAIL; BAR(); \
} while (0)

__global__ __launch_bounds__(512, 2) void gemm8p(
    const unsigned short* __restrict__ A,
    const unsigned short* __restrict__ W,
    float* __restrict__ Y) {
  __shared__ char lds[98304];
  const int tid = threadIdx.x;
  const int lane = tid & 63;
  const int wave = tid >> 6;  // 0..7
  const int wm = wave >> 2;   // 0..1
  const int wn = wave & 3;    // 0..3

  // XCD-aware bijective swizzle (256 blocks % 8 == 0)
  const int sw = ((blockIdx.x & 7) << 5) | (blockIdx.x >> 3);
  const int bcol = (sw >> 5) * 256;  // 0..7 -> out cols
  const int brow = (sw & 31) * 128;  // 0..31 -> batch rows

  // staging: thread covers row = i*64 + wave*8 + (lane>>3), 16B slot gc16 (pre-swizzled)
  const int srow = wave * 8 + (lane >> 3);
  const int gc16 = (lane & 7) ^ (lane >> 3);
  const char* aS  = (const char*)A + (size_t)(brow + srow) * KROWB + gc16 * 16;
  const char* bS0 = (const char*)W + (size_t)(bcol + srow) * KROWB + gc16 * 16;
  const char* bS1 = bS0 + (size_t)128 * KROWB;
  const int ldsl = wave * 1024;  // + lane*16 implicit in global_load_lds

  // fragment read offsets (swizzled): byte = row*128 + ((c16 ^ (row&7))<<4)
  const int rA = (wm * 64 + (lane & 15)) * 128;
  const int rB = ((wn & 1) * 64 + (lane & 15)) * 128;
  const int bu = 16384 + (wn >> 1) * 16384;  // B unit: wn<2 -> B0, else B1
  const int s0 = (((lane >> 4)    ) ^ (lane & 7)) << 4;  // kk=0
  const int s1 = ((4 + (lane >> 4)) ^ (lane & 7)) << 4;  // kk=1

  f32x4 acc[4][4];
#pragma unroll
  for (int m = 0; m < 4; ++m)
#pragma unroll
    for (int n = 0; n < 4; ++n)
      acc[m][n] = (f32x4){0.f, 0.f, 0.f, 0.f};
  bf16x8 a0[2][2], a1[2][2], b0f[2][2], b1f[2][2];

  // prologue: stage tiles 0 (parity 0) and 1 (parity 1), order B0,B1,A per tile
  STAGE(16384, bS0, 0); STAGE(32768, bS1, 0); STAGE(0, aS, 0);
  STAGE(49152 + 16384, bS0, 1); STAGE(49152 + 32768, bS1, 1); STAGE(49152, aS, 1);
  VMW6(); BAR();

  for (int t = 0; t < NT - 2; t += 2) {
    KTILE(0, t, 1, VMW6());
    KTILE(1, t + 1, 1, VMW6());
  }
  KTILE(0, NT - 2, 0, VMW0());  // ensure last tile's loads landed
  KTILE(1, NT - 1, 0, VMW0());

  // epilogue: C/D layout col = lane&15, row = (lane>>4)*4 + j
  const int r0 = brow + wm * 64 + (lane >> 4) * 4;
  const int c0 = bcol + wn * 64 + (lane & 15);
#pragma unroll
  for (int m = 0; m < 4; ++m)
#pragma unroll
    for (int n = 0; n < 4; ++n)
#pragma unroll
      for (int j = 0; j < 4; ++j)
        Y[(size_t)(r0 + m * 16 + j) * OUT_DIM + (c0 + n * 16)] = acc[m][n][j];
}

// K3a: per-column sums / sums-of-squares over batch (atomics into ws)
__global__ void colstats(const float* __restrict__ Y,
                         float* __restrict__ sums, float* __restrict__ sqs) {
  int col = (blockIdx.x & 7) * 256 + threadIdx.x;
  int r0 = (blockIdx.x >> 3) * 128;
  float s = 0.f, q = 0.f;
  for (int r = 0; r < 128; ++r) {
    float v = Y[(size_t)(r0 + r) * OUT_DIM + col];
    s += v;
    q += v * v;
  }
  atomicAdd(&sums[col], s);
  atomicAdd(&sqs[col], q);
}

// K3b: in-place batchnorm on Y
__global__ void bnorm(float* __restrict__ Y,
                      const float* __restrict__ sums, const float* __restrict__ sqs,
                      const float* __restrict__ gamma, const float* __restrict__ beta) {
  int e = (blockIdx.x * 256 + threadIdx.x) * 4;
  int c = e % OUT_DIM;
  float4 y = *(float4*)(Y + e);
  float4 s = *(const float4*)(sums + c);
  float4 q = *(const float4*)(sqs + c);
  float4 g = *(const float4*)(gamma + c);
  float4 bb = *(const float4*)(beta + c);
  const float invB = 1.0f / (float)BATCH;
  float m0 = s.x * invB, m1 = s.y * invB, m2 = s.z * invB, m3 = s.w * invB;
  float i0 = rsqrtf(q.x * invB - m0 * m0 + BN_EPS);
  float i1 = rsqrtf(q.y * invB - m1 * m1 + BN_EPS);
  float i2 = rsqrtf(q.z * invB - m2 * m2 + BN_EPS);
  float i3 = rsqrtf(q.w * invB - m3 * m3 + BN_EPS);
  y.x = g.x * (y.x - m0) * i0 + bb.x;
  y.y = g.y * (y.y - m1) * i1 + bb.y;
  y.z = g.z * (y.z - m2) * i2 + bb.z;
  y.w = g.w * (y.w - m3) * i3 + bb.w;
  *(float4*)(Y + e) = y;
}

extern "C" void kernel_launch(void* const* d_in, const int* in_sizes, int n_in,
                              void* d_out, int out_size, void* d_ws, size_t ws_size,
                              hipStream_t stream) {
  const float* x         = (const float*)d_in[0];
  const float* scale     = (const float*)d_in[1];
  const float* translate = (const float*)d_in[2];
  const float* ww        = (const float*)d_in[3];
  const float* bw        = (const float*)d_in[4];
  const float* gamma     = (const float*)d_in[5];
  const float* beta      = (const float*)d_in[6];
  float* out = (float*)d_out;

  char* ws = (char*)d_ws;
  unsigned short* A = (unsigned short*)ws;               // 33,554,432 B
  unsigned short* W = (unsigned short*)(ws + 33554432);  // 16,777,216 B
  float* sums = (float*)(ws + 33554432 + 16777216);
  float* sqs = sums + OUT_DIM;

  hipMemsetAsync(sums, 0, 2 * OUT_DIM * sizeof(float), stream);
  prep_act<<<(BATCH * IN_DIM) / 1024, 256, 0, stream>>>(x, scale, translate, A);
  prep_w<<<(OUT_DIM * IN_DIM) / 1024, 256, 0, stream>>>(ww, bw, W);
  gemm8p<<<256, 512, 0, stream>>>(A, W, out);
  colstats<<<256, 256, 0, stream>>>(out, sums, sqs);
  bnorm<<<(BATCH * OUT_DIM) / 1024, 256, 0, stream>>>(out, sums, sqs, gamma, beta);
}